// Round 5
// baseline (331.797 us; speedup 1.0000x reference)
//
#include <hip/hip_runtime.h>
#include <stdint.h>

#define B_   16
#define S_   1024
#define N_   4096
#define C_   768
#define OUT_ 256

typedef short bf16x8 __attribute__((ext_vector_type(8)));
typedef short bf16x4 __attribute__((ext_vector_type(4)));
typedef float f32x4  __attribute__((ext_vector_type(4)));

#define GLOBAL_AS __attribute__((address_space(1)))
#define LDS_AS    __attribute__((address_space(3)))

__device__ __forceinline__ unsigned short f2bf(float f) {
    unsigned int u = __float_as_uint(f);
    u += 0x7fffu + ((u >> 16) & 1u);   // round-to-nearest-even
    return (unsigned short)(u >> 16);
}

__device__ __forceinline__ void gl_lds16(const void* gsrc, void* ldst) {
    __builtin_amdgcn_global_load_lds((const GLOBAL_AS void*)gsrc,
                                     (LDS_AS void*)ldst, 16, 0, 0);
}

// ---------------------------------------------------------------------------
// K0: W fp32 -> bf16
// ---------------------------------------------------------------------------
__global__ __launch_bounds__(256) void k_wconv(const float* __restrict__ W,
                                               unsigned short* __restrict__ Wb) {
    int i = blockIdx.x * 256 + threadIdx.x;
    Wb[i] = f2bf(W[i]);
}

// ---------------------------------------------------------------------------
// K1 (ROUND 5): fused pgemm + argmin.
// Blocks bid%3==2 (256 of them): argmin for 64 seeds each (16 seeds/wave).
// Other 512: P[b][n][o] = bf16(sum_c f[b][c][n]*Wb[o][c]), n-blk 128, o 256,
// BK=32, DOUBLE-BUFFERED: stage kt+1 (W via global_load_lds, f via f32x4 +
// in-register 4x4 transpose) before computing kt -> barrier drain overlaps
// compute. argmin blocks co-resident with pgemm blocks hide VALU under mem.
// ---------------------------------------------------------------------------
__global__ __launch_bounds__(256, 2) void k_fused(const float* __restrict__ f,
                                                  const unsigned short* __restrict__ Wb,
                                                  const float* __restrict__ seed,
                                                  const float* __restrict__ pl,
                                                  unsigned short* __restrict__ P,
                                                  int* __restrict__ idx_out) {
    __shared__ unsigned short ldsF[2][128 * 36];   // [n][k] 2x9216 shorts
    __shared__ unsigned short ldsW[2][256 * 32];   // [o][k] 2x8192 shorts
    const int t   = threadIdx.x;
    const int bid = blockIdx.x;
    const int q   = bid / 3;
    const int r   = bid - q * 3;

    if (r == 2) {
        // ---------------- argmin path: block q of 256, 64 seeds ----------
        const int lane = t & 63;
        const int w    = t >> 6;
        const int b    = q >> 4;
        const int s0   = (q & 15) * 64 + w * 16;

        float sx[16], sy[16], sz[16], s2[16], best[16];
        int   bidx[16];
#pragma unroll
        for (int j = 0; j < 16; ++j) {
            const float* sp = seed + (size_t)(b * S_ + s0 + j) * 3;
            sx[j] = sp[0]; sy[j] = sp[1]; sz[j] = sp[2];
            s2[j] = __fadd_rn(__fadd_rn(__fmul_rn(sx[j], sx[j]),
                                        __fmul_rn(sy[j], sy[j])),
                              __fmul_rn(sz[j], sz[j]));
            best[j] = 3.4e38f;
            bidx[j] = 0;
        }
        const float* pb = pl + (size_t)b * N_ * 3;
        for (int k = 0; k < N_ / 64; ++k) {
            const int   n  = k * 64 + lane;
            const float px = pb[n * 3 + 0];
            const float py = pb[n * 3 + 1];
            const float pz = pb[n * 3 + 2];
            const float p2 = __fadd_rn(__fadd_rn(__fmul_rn(px, px),
                                                 __fmul_rn(py, py)),
                                       __fmul_rn(pz, pz));
#pragma unroll
            for (int j = 0; j < 16; ++j) {
                float dot = __fadd_rn(__fadd_rn(__fmul_rn(sx[j], px),
                                                __fmul_rn(sy[j], py)),
                                      __fmul_rn(sz[j], pz));
                float d2  = __fadd_rn(__fsub_rn(s2[j], __fmul_rn(2.0f, dot)), p2);
                if (d2 < best[j]) { best[j] = d2; bidx[j] = n; }
            }
        }
#pragma unroll
        for (int j = 0; j < 16; ++j) {
#pragma unroll
            for (int off = 32; off >= 1; off >>= 1) {
                float ob = __shfl_xor(best[j], off, 64);
                int   oi = __shfl_xor(bidx[j], off, 64);
                bool take = (ob < best[j]) || (ob == best[j] && oi < bidx[j]);
                if (take) { best[j] = ob; bidx[j] = oi; }
            }
            if (lane == 0) idx_out[b * S_ + s0 + j] = bidx[j];
        }
        return;
    }

    // ---------------- pgemm path: pid of 512 ----------------------------
    const int pid  = q * 2 + r;
    const int b    = pid >> 5;
    const int n0   = (pid & 31) * 128;
    const int lane = t & 63;
    const int w    = t >> 6;
    const int wm   = w & 1;           // n-half
    const int wo   = w >> 1;          // o-half
    const int quad = lane >> 4, l16 = lane & 15;

    f32x4 acc[4][8];
#pragma unroll
    for (int i = 0; i < 4; ++i)
#pragma unroll
        for (int j = 0; j < 8; ++j) acc[i][j] = (f32x4){0.f, 0.f, 0.f, 0.f};

    const int cb = t >> 5;            // 0..7  (4-c block)
    const int nb = t & 31;            // 0..31 (4-n block)
    const float* fB = f + (size_t)b * C_ * N_ + n0 + nb * 4;
    const unsigned short* wSrc = Wb + (size_t)(t >> 2) * C_ + (t & 3) * 8;

    f32x4 v[4];
    // ---- prologue: stage kt=0 into buf 0 ----
#pragma unroll
    for (int i = 0; i < 4; ++i)
        gl_lds16(wSrc + (size_t)i * 64 * C_, &ldsW[0][i * 2048 + t * 8]);
#pragma unroll
    for (int j = 0; j < 4; ++j)
        v[j] = *(const f32x4*)(fB + (size_t)(cb * 4 + j) * N_);
#pragma unroll
    for (int i = 0; i < 4; ++i) {
        bf16x4 pk = {(short)f2bf(v[0][i]), (short)f2bf(v[1][i]),
                     (short)f2bf(v[2][i]), (short)f2bf(v[3][i])};
        *(bf16x4*)&ldsF[0][(nb * 4 + i) * 36 + cb * 4] = pk;
    }
    __syncthreads();

    for (int kt = 0; kt < 24; ++kt) {
        const int cur = kt & 1, nxt = cur ^ 1;
        const bool pre = (kt + 1 < 24);
        if (pre) {
            const int k0 = (kt + 1) * 32;
#pragma unroll
            for (int i = 0; i < 4; ++i)
                gl_lds16(wSrc + (size_t)i * 64 * C_ + k0, &ldsW[nxt][i * 2048 + t * 8]);
#pragma unroll
            for (int j = 0; j < 4; ++j)
                v[j] = *(const f32x4*)(fB + (size_t)(k0 + cb * 4 + j) * N_);
        }

        bf16x8 aF[4], bF[8];
#pragma unroll
        for (int mi = 0; mi < 4; ++mi) {
            const unsigned short* p = &ldsF[cur][(wm * 64 + mi * 16 + l16) * 36 + quad * 8];
            bf16x4 lo = *(const bf16x4*)p;
            bf16x4 hi = *(const bf16x4*)(p + 4);
            aF[mi] = __builtin_shufflevector(lo, hi, 0, 1, 2, 3, 4, 5, 6, 7);
        }
#pragma unroll
        for (int oi = 0; oi < 8; ++oi)
            bF[oi] = *(const bf16x8*)&ldsW[cur][(wo * 128 + oi * 16 + l16) * 32 + quad * 8];
#pragma unroll
        for (int mi = 0; mi < 4; ++mi)
#pragma unroll
            for (int oi = 0; oi < 8; ++oi)
                acc[mi][oi] = __builtin_amdgcn_mfma_f32_16x16x32_bf16(
                    aF[mi], bF[oi], acc[mi][oi], 0, 0, 0);

        if (pre) {
#pragma unroll
            for (int i = 0; i < 4; ++i) {
                bf16x4 pk = {(short)f2bf(v[0][i]), (short)f2bf(v[1][i]),
                             (short)f2bf(v[2][i]), (short)f2bf(v[3][i])};
                *(bf16x4*)&ldsF[nxt][(nb * 4 + i) * 36 + cb * 4] = pk;
            }
        }
        __syncthreads();
    }

    // epilogue: D row = n (A side), col = o (B side); store bf16
    unsigned short* Pb = P + ((size_t)b * N_ + n0) * OUT_;
#pragma unroll
    for (int mi = 0; mi < 4; ++mi) {
#pragma unroll
        for (int rr = 0; rr < 4; ++rr) {
            const int n = wm * 64 + mi * 16 + quad * 4 + rr;
            unsigned short* row = Pb + (size_t)n * OUT_;
#pragma unroll
            for (int oi = 0; oi < 8; ++oi) {
                const int o = wo * 128 + oi * 16 + l16;
                row[o] = f2bf(acc[mi][oi][rr]);
            }
        }
    }
}

// ---------------------------------------------------------------------------
// K2: out[b][o][s] = f32(P[b][idx[b][s]][o]) + bias[o]
// Coalesced 512B row-gather -> LDS [s][o] (rowB=260) -> transposed store.
// ---------------------------------------------------------------------------
__global__ __launch_bounds__(256) void k_out(const unsigned short* __restrict__ P,
                                             const int* __restrict__ idx,
                                             const float* __restrict__ bias,
                                             float* __restrict__ out) {
    __shared__ unsigned short tl[64 * 260];
    const int t  = threadIdx.x;
    const int b  = blockIdx.x >> 4;
    const int st = blockIdx.x & 15;
    const int s0 = st * 64;
    const unsigned short* Pb = P + (size_t)b * N_ * OUT_;

#pragma unroll
    for (int i = 0; i < 8; ++i) {
        const int g = i * 256 + t;
        const int s = g >> 5;
        const int p = g & 31;
        const int n = idx[b * S_ + s0 + s];
        const unsigned short* src = Pb + (size_t)n * OUT_ + p * 8;
        uint2 u0 = *(const uint2*)src;
        uint2 u1 = *(const uint2*)(src + 4);
        *(uint2*)(tl + s * 260 + p * 8)     = u0;
        *(uint2*)(tl + s * 260 + p * 8 + 4) = u1;
    }
    __syncthreads();

    const int lane = t & 63;
    const int w    = t >> 6;
    float* ob = out + (size_t)b * OUT_ * S_ + s0;
#pragma unroll 4
    for (int oo = 0; oo < 64; ++oo) {
        const int o = w * 64 + oo;
        const unsigned short u = tl[lane * 260 + o];
        const float val = __uint_as_float(((unsigned int)u) << 16) + bias[o];
        ob[(size_t)o * S_ + lane] = val;
    }
}

// ---------------------------------------------------------------------------
// Workspace: [0,64K) idx int32[16][1024]
//            [64K,64K+384K) Wb bf16[256][768]
//            [512K, 512K+33.6MB) P bf16[16][4096][256]
// ---------------------------------------------------------------------------
extern "C" void kernel_launch(void* const* d_in, const int* in_sizes, int n_in,
                              void* d_out, int out_size, void* d_ws, size_t ws_size,
                              hipStream_t stream) {
    const float* seed = (const float*)d_in[0];   // [16,1024,3]
    const float* pl   = (const float*)d_in[1];   // [16,4096,3]
    const float* f    = (const float*)d_in[2];   // [16,768,4096]
    const float* W    = (const float*)d_in[3];   // [256,768]
    const float* bias = (const float*)d_in[4];   // [256]
    float* out = (float*)d_out;                  // [16,256,1024] fp32

    int* idx            = (int*)d_ws;
    unsigned short* Wb  = (unsigned short*)((char*)d_ws + 65536);
    unsigned short* P   = (unsigned short*)((char*)d_ws + 524288);

    k_wconv<<<768, 256, 0, stream>>>(W, Wb);
    k_fused<<<768, 256, 0, stream>>>(f, Wb, seed, pl, P, idx);
    k_out  <<<256, 256, 0, stream>>>(P, idx, bias, out);
}